// Round 1
// baseline (10878.436 us; speedup 1.0000x reference)
//
#include <hip/hip_runtime.h>

static constexpr int B = 32, N = 2048, BN = B * N;

#define DEV static __device__ __forceinline__

DEV float lk(float v) { return v >= 0.f ? v : 0.01f * v; }
DEV bool lexlt(float d1, int j1, float d2, int j2) {
    return d1 < d2 || (d1 == d2 && j1 < j2);
}
DEV bool lexgt(float d1, int j1, float d2, int j2) {
    return d1 > d2 || (d1 == d2 && j1 > j2);
}

// ---------------------------------------------------------------- build xx
__global__ __launch_bounds__(256) void k_build_xx(const float* __restrict__ x,
                                                  const float* __restrict__ pos,
                                                  float* __restrict__ xx) {
    int i = blockIdx.x * 256 + threadIdx.x;
    if (i < BN) {
        float4 v;
        v.x = x[i];
        v.y = pos[3 * i + 0];
        v.z = pos[3 * i + 1];
        v.w = pos[3 * i + 2];
        ((float4*)xx)[i] = v;
    }
}

// ------------------------------------------------- knn(F=4) + homophily + conv1 idx
// one wave per row; extracts 51 smallest (d, j) lex-ascending.
// first 5 -> c1idx (self included naturally, d_self = 0);
// non-self extractions (up to 50) -> homophily equality counts.
__global__ __launch_bounds__(256) void k_knn4(const float* __restrict__ xx,
                                              int* __restrict__ c1idx,
                                              unsigned int* __restrict__ hcnt) {
    int gw = (blockIdx.x * 256 + threadIdx.x) >> 6;  // global row id
    int lane = threadIdx.x & 63;
    int g = gw >> 11, i = gw & 2047;
    const float4* base = ((const float4*)xx) + g * N;
    float4 xi = base[i];
    float si = xi.x * xi.x + xi.y * xi.y + xi.z * xi.z + xi.w * xi.w;
    float d[32];
#pragma unroll
    for (int t = 0; t < 32; t++) {
        float4 xj = base[lane + 64 * t];
        float sj = xj.x * xj.x + xj.y * xj.y + xj.z * xj.z + xj.w * xj.w;
        float dot = xi.x * xj.x + xi.y * xj.y + xi.z * xj.z + xi.w * xj.w;
        d[t] = (si + sj) - 2.f * dot;
    }
    // per-lane sorted top-4 cache (ascending, lex (d, j))
    float Lv[4];
    int Lj[4];
#pragma unroll
    for (int s = 0; s < 4; s++) { Lv[s] = __builtin_inff(); Lj[s] = 0x7fffffff; }
#pragma unroll
    for (int t = 0; t < 32; t++) {
        float v = d[t];
        int j = lane + 64 * t;
        if (lexlt(v, j, Lv[3], Lj[3])) {
            Lv[3] = v; Lj[3] = j;
#pragma unroll
            for (int s = 3; s >= 1; s--)
                if (lexlt(Lv[s], Lj[s], Lv[s - 1], Lj[s - 1])) {
                    float tv = Lv[s]; Lv[s] = Lv[s - 1]; Lv[s - 1] = tv;
                    int tj = Lj[s]; Lj[s] = Lj[s - 1]; Lj[s - 1] = tj;
                }
        }
    }
    int c0 = 0, c1 = 0, c2 = 0, c3 = 0, hc = 0;
    for (int r = 0; r < 51; r++) {
        float bv = Lv[0];
        int bj = Lj[0];
#pragma unroll
        for (int o = 1; o < 64; o <<= 1) {
            float ov = __shfl_xor(bv, o);
            int oj = __shfl_xor(bj, o);
            if (lexlt(ov, oj, bv, bj)) { bv = ov; bj = oj; }
        }
        if (r < 5 && lane == 0) c1idx[gw * 5 + r] = bj;
        if (bj != i && hc < 50) {
            hc++;
            if (lane == 0) {
                float4 xj = base[bj];
                c0 += (xj.x == xi.x); c1 += (xj.y == xi.y);
                c2 += (xj.z == xi.z); c3 += (xj.w == xi.w);
            }
        }
        // winner lane consumes its head; refill from d[] if its cache empties
        if (Lv[0] == bv && Lj[0] == bj) {
            Lv[0] = Lv[1]; Lv[1] = Lv[2]; Lv[2] = Lv[3]; Lv[3] = __builtin_inff();
            Lj[0] = Lj[1]; Lj[1] = Lj[2]; Lj[2] = Lj[3]; Lj[3] = 0x7fffffff;
            if (Lv[0] == __builtin_inff() && Lj[0] == 0x7fffffff) {
#pragma unroll
                for (int t = 0; t < 32; t++) {
                    float v = d[t];
                    int j = lane + 64 * t;
                    if (lexgt(v, j, bv, bj) && lexlt(v, j, Lv[3], Lj[3])) {
                        Lv[3] = v; Lj[3] = j;
#pragma unroll
                        for (int s = 3; s >= 1; s--)
                            if (lexlt(Lv[s], Lj[s], Lv[s - 1], Lj[s - 1])) {
                                float tv = Lv[s]; Lv[s] = Lv[s - 1]; Lv[s - 1] = tv;
                                int tj = Lj[s]; Lj[s] = Lj[s - 1]; Lj[s - 1] = tj;
                            }
                    }
                }
            }
        }
    }
    if (lane == 0) {
        unsigned int* hp = hcnt + g * 4;
        atomicAdd(hp + 0, (unsigned)c0);
        atomicAdd(hp + 1, (unsigned)c1);
        atomicAdd(hp + 2, (unsigned)c2);
        atomicAdd(hp + 3, (unsigned)c3);
    }
}

// ---------------------------------------------------------------- squared norms
__global__ __launch_bounds__(256) void k_sq(const float* __restrict__ X,
                                            float* __restrict__ s) {
    int n = blockIdx.x * 256 + threadIdx.x;
    const float4* r = (const float4*)(X + (size_t)n * 64);
    float acc = 0.f;
#pragma unroll
    for (int t = 0; t < 16; t++) {
        float4 v = r[t];
        acc += v.x * v.x + v.y * v.y + v.z * v.z + v.w * v.w;
    }
    s[n] = acc;
}

// ----------------------------------------- node-level layer-1 split: p = x(Wa-Wb)+b1, q = x Wb
template <int F, int C>
__global__ __launch_bounds__(256) void k_pq(const float* __restrict__ X,
                                            const float* __restrict__ w1,
                                            const float* __restrict__ b1,
                                            float* __restrict__ p,
                                            float* __restrict__ q) {
    constexpr int FS = F + 4;
    __shared__ __align__(16) float Xs[64 * FS];
    __shared__ __align__(16) float Ws[64 * FS];
    int nbase = blockIdx.x * 64;
    int cchunk = blockIdx.y;
    int tx = threadIdx.x & 15, ty = threadIdx.x >> 4;
    for (int idx = threadIdx.x; idx < 64 * F; idx += 256) {
        int r = idx / F, f = idx % F;
        Xs[r * FS + f] = X[(size_t)(nbase + r) * F + f];
    }
    for (int idx = threadIdx.x; idx < 64 * F; idx += 256) {
        int f = idx >> 6, cl = idx & 63;
        int ccg = cchunk * 64 + cl;
        float v;
        if (ccg < C) v = w1[f * C + ccg] - w1[(F + f) * C + ccg];
        else         v = w1[(F + f) * C + (ccg - C)];
        Ws[cl * FS + f] = v;
    }
    __syncthreads();
    float acc[4][4];
#pragma unroll
    for (int a = 0; a < 4; a++)
#pragma unroll
        for (int b = 0; b < 4; b++) acc[a][b] = 0.f;
#pragma unroll
    for (int fs = 0; fs < F / 4; fs++) {
        float4 xv[4], wv[4];
#pragma unroll
        for (int a = 0; a < 4; a++) xv[a] = *(const float4*)&Xs[(ty + 16 * a) * FS + fs * 4];
#pragma unroll
        for (int b = 0; b < 4; b++) wv[b] = *(const float4*)&Ws[(tx + 16 * b) * FS + fs * 4];
#pragma unroll
        for (int a = 0; a < 4; a++)
#pragma unroll
            for (int b = 0; b < 4; b++) {
                acc[a][b] = fmaf(xv[a].x, wv[b].x, acc[a][b]);
                acc[a][b] = fmaf(xv[a].y, wv[b].y, acc[a][b]);
                acc[a][b] = fmaf(xv[a].z, wv[b].z, acc[a][b]);
                acc[a][b] = fmaf(xv[a].w, wv[b].w, acc[a][b]);
            }
    }
#pragma unroll
    for (int a = 0; a < 4; a++) {
        int n = nbase + ty + 16 * a;
#pragma unroll
        for (int b = 0; b < 4; b++) {
            int ccg = cchunk * 64 + tx + 16 * b;
            if (ccg < C) p[(size_t)n * C + ccg] = acc[a][b] + b1[ccg];
            else         q[(size_t)n * C + (ccg - C)] = acc[a][b];
        }
    }
}

// --------------------------------- per-edge layer 2: h2 = leaky(h1 @ w2 + b2), sum over k=5
// h1[e][l] = leaky(p[i_e][l] + q[j_e][l]), built in LDS; 16 nodes (80 edges) per block.
template <int C1>
__global__ __launch_bounds__(256) void k_edge(const float* __restrict__ p,
                                              const float* __restrict__ q,
                                              const int* __restrict__ cidx,
                                              const float* __restrict__ w2,
                                              const float* __restrict__ b2,
                                              float* __restrict__ Xout) {
    __shared__ __align__(16) float h1[80 * 68];
    __shared__ __align__(16) float w2T[64 * 68];
    int nb = blockIdx.x * 16;
    int gb = (nb >> 11) << 11;  // graph base node
    int tx = threadIdx.x & 15, ty = threadIdx.x >> 4;
    float acc[5][4];
#pragma unroll
    for (int m = 0; m < 5; m++)
#pragma unroll
        for (int n = 0; n < 4; n++) acc[m][n] = 0.f;
#pragma unroll
    for (int half = 0; half < C1 / 64; half++) {
        __syncthreads();
        for (int idx = threadIdx.x; idx < 64 * 64; idx += 256) {
            int l = idx >> 6, c = idx & 63;
            w2T[c * 68 + l] = w2[(half * 64 + l) * 64 + c];
        }
        for (int idx = threadIdx.x; idx < 80 * 64; idx += 256) {
            int e = idx >> 6, l = idx & 63;
            int node = nb + e / 5, kk = e - 5 * (e / 5);
            int j = cidx[node * 5 + kk];
            h1[e * 68 + l] = lk(p[(size_t)node * C1 + half * 64 + l] +
                                q[(size_t)(gb + j) * C1 + half * 64 + l]);
        }
        __syncthreads();
#pragma unroll
        for (int ls = 0; ls < 16; ls++) {
            float4 hv[5], wf[4];
#pragma unroll
            for (int m = 0; m < 5; m++) hv[m] = *(const float4*)&h1[(ty + 16 * m) * 68 + ls * 4];
#pragma unroll
            for (int n = 0; n < 4; n++) wf[n] = *(const float4*)&w2T[(tx + 16 * n) * 68 + ls * 4];
#pragma unroll
            for (int m = 0; m < 5; m++)
#pragma unroll
                for (int n = 0; n < 4; n++) {
                    acc[m][n] = fmaf(hv[m].x, wf[n].x, acc[m][n]);
                    acc[m][n] = fmaf(hv[m].y, wf[n].y, acc[m][n]);
                    acc[m][n] = fmaf(hv[m].z, wf[n].z, acc[m][n]);
                    acc[m][n] = fmaf(hv[m].w, wf[n].w, acc[m][n]);
                }
        }
    }
    float b2r[4];
#pragma unroll
    for (int n = 0; n < 4; n++) b2r[n] = b2[tx + 16 * n];
    __syncthreads();  // all h1 reads done; reuse h1 region for h2
    float* h2 = h1;
#pragma unroll
    for (int m = 0; m < 5; m++)
#pragma unroll
        for (int n = 0; n < 4; n++)
            h2[(ty + 16 * m) * 68 + (tx + 16 * n)] = lk(acc[m][n] + b2r[n]);
    __syncthreads();
#pragma unroll
    for (int rr = 0; rr < 4; rr++) {
        int idx = threadIdx.x + 256 * rr;
        int node = idx >> 6, c = idx & 63;
        float sum = 0.f;
#pragma unroll
        for (int kk = 0; kk < 5; kk++) sum += h2[(node * 5 + kk) * 68 + c];
        Xout[(size_t)(nb + node) * 64 + c] = sum;
    }
}

// --------------------------------------------- knn over F=64 features, top-5 (self incl.)
__global__ __launch_bounds__(256) void k_knn64(const float* __restrict__ X,
                                               const float* __restrict__ s,
                                               int* __restrict__ cidx) {
    __shared__ __align__(16) float Xi[64 * 68];
    __shared__ __align__(16) float XjB[10240];  // Xj (4352 f) during loop; cand after
    __shared__ float sI[64], sJ[64];
    int it = blockIdx.x, g = blockIdx.y;
    int gbase = g * 2048, ibase = it * 64;
    int tx = threadIdx.x & 15, ty = threadIdx.x >> 4;
    float* Xj = XjB;
    for (int idx = threadIdx.x; idx < 64 * 64; idx += 256) {
        int r = idx >> 6, f = idx & 63;
        Xi[r * 68 + f] = X[(size_t)(gbase + ibase + r) * 64 + f];
    }
    if (threadIdx.x < 64) sI[threadIdx.x] = s[gbase + ibase + threadIdx.x];
    __syncthreads();
    float si_r[4];
#pragma unroll
    for (int a = 0; a < 4; a++) si_r[a] = sI[ty + 16 * a];
    float t5v[4][5];
    int t5j[4][5];
#pragma unroll
    for (int a = 0; a < 4; a++)
#pragma unroll
        for (int ss = 0; ss < 5; ss++) { t5v[a][ss] = __builtin_inff(); t5j[a][ss] = 0x7fffffff; }
    for (int jt = 0; jt < 32; jt++) {
        __syncthreads();
        for (int idx = threadIdx.x; idx < 64 * 64; idx += 256) {
            int r = idx >> 6, f = idx & 63;
            Xj[r * 68 + f] = X[(size_t)(gbase + jt * 64 + r) * 64 + f];
        }
        if (threadIdx.x < 64) sJ[threadIdx.x] = s[gbase + jt * 64 + threadIdx.x];
        __syncthreads();
        float sj_r[4];
#pragma unroll
        for (int b = 0; b < 4; b++) sj_r[b] = sJ[tx + 16 * b];
        float acc[4][4];
#pragma unroll
        for (int a = 0; a < 4; a++)
#pragma unroll
            for (int b = 0; b < 4; b++) acc[a][b] = 0.f;
#pragma unroll
        for (int fs = 0; fs < 16; fs++) {
            float4 xa[4], xb[4];
#pragma unroll
            for (int a = 0; a < 4; a++) xa[a] = *(const float4*)&Xi[(ty + 16 * a) * 68 + fs * 4];
#pragma unroll
            for (int b = 0; b < 4; b++) xb[b] = *(const float4*)&Xj[(tx + 16 * b) * 68 + fs * 4];
#pragma unroll
            for (int a = 0; a < 4; a++)
#pragma unroll
                for (int b = 0; b < 4; b++) {
                    acc[a][b] = fmaf(xa[a].x, xb[b].x, acc[a][b]);
                    acc[a][b] = fmaf(xa[a].y, xb[b].y, acc[a][b]);
                    acc[a][b] = fmaf(xa[a].z, xb[b].z, acc[a][b]);
                    acc[a][b] = fmaf(xa[a].w, xb[b].w, acc[a][b]);
                }
        }
#pragma unroll
        for (int a = 0; a < 4; a++)
#pragma unroll
            for (int b = 0; b < 4; b++) {
                float dv = (si_r[a] + sj_r[b]) - 2.f * acc[a][b];
                int jv = jt * 64 + tx + 16 * b;
                if (lexlt(dv, jv, t5v[a][4], t5j[a][4])) {
                    t5v[a][4] = dv; t5j[a][4] = jv;
#pragma unroll
                    for (int ss = 4; ss >= 1; ss--)
                        if (lexlt(t5v[a][ss], t5j[a][ss], t5v[a][ss - 1], t5j[a][ss - 1])) {
                            float tv = t5v[a][ss]; t5v[a][ss] = t5v[a][ss - 1]; t5v[a][ss - 1] = tv;
                            int tj = t5j[a][ss]; t5j[a][ss] = t5j[a][ss - 1]; t5j[a][ss - 1] = tj;
                        }
                }
            }
    }
    __syncthreads();  // done with Xj; reuse as candidate buffer
    float* candd = XjB;
    int* candj = (int*)(XjB + 5120);
#pragma unroll
    for (int a = 0; a < 4; a++) {
        int row = ty + 16 * a;
#pragma unroll
        for (int ss = 0; ss < 5; ss++) {
            candd[row * 80 + tx * 5 + ss] = t5v[a][ss];
            candj[row * 80 + tx * 5 + ss] = t5j[a][ss];
        }
    }
    __syncthreads();
    if (threadIdx.x < 64) {
        int row = threadIdx.x;
        float fv[5];
        int fj[5];
#pragma unroll
        for (int ss = 0; ss < 5; ss++) { fv[ss] = __builtin_inff(); fj[ss] = 0x7fffffff; }
        for (int c = 0; c < 80; c++) {
            float dv = candd[row * 80 + c];
            int jv = candj[row * 80 + c];
            if (lexlt(dv, jv, fv[4], fj[4])) {
                fv[4] = dv; fj[4] = jv;
#pragma unroll
                for (int ss = 4; ss >= 1; ss--)
                    if (lexlt(fv[ss], fj[ss], fv[ss - 1], fj[ss - 1])) {
                        float tv = fv[ss]; fv[ss] = fv[ss - 1]; fv[ss - 1] = tv;
                        int tj = fj[ss]; fj[ss] = fj[ss - 1]; fj[ss - 1] = tj;
                    }
            }
        }
#pragma unroll
        for (int ss = 0; ss < 5; ss++)
            cidx[(size_t)(gbase + ibase + row) * 5 + ss] = fj[ss];
    }
}

// ------------------------- lin1 layer1 + leaky + mean-pool accumulate (no atomics)
// block = (cchunk 0..7, graph); 64 couts; f split 100+96 to fit 64KB LDS.
__global__ __launch_bounds__(256) void k_lin1(const float* __restrict__ xx,
                                              const float* __restrict__ x1,
                                              const float* __restrict__ x2,
                                              const float* __restrict__ x3,
                                              const float* __restrict__ w1,
                                              const float* __restrict__ b1,
                                              float* __restrict__ Hsum) {
    __shared__ __align__(16) float ft[64 * 100];
    __shared__ __align__(16) float wT[64 * 100];
    int cch = blockIdx.x, g = blockIdx.y;
    int gbase = g * 2048;
    int tx = threadIdx.x & 15, ty = threadIdx.x >> 4;
    float b1r[4];
#pragma unroll
    for (int ca = 0; ca < 4; ca++) b1r[ca] = b1[cch * 64 + tx + 16 * ca];
    float psum[4] = {0.f, 0.f, 0.f, 0.f};
    for (int nt = 0; nt < 32; nt++) {
        int n0 = nt * 64;
        float acc[4][4];
#pragma unroll
        for (int rm = 0; rm < 4; rm++)
#pragma unroll
            for (int ca = 0; ca < 4; ca++) acc[rm][ca] = 0.f;
        for (int half = 0; half < 2; half++) {
            int fb = half * 100;
            int FH = half ? 96 : 100;
            __syncthreads();
            for (int idx = threadIdx.x; idx < 64 * 100; idx += 256) {
                int f = idx >> 6, cl = idx & 63;
                if (f < FH) wT[cl * 100 + f] = w1[(fb + f) * 512 + cch * 64 + cl];
            }
            for (int idx = threadIdx.x; idx < 64 * 100; idx += 256) {
                int r = idx / 100, f = idx - r * 100;
                if (f < FH) {
                    int fg = fb + f;
                    int node = gbase + n0 + r;
                    float v;
                    if (fg < 4)        v = xx[(size_t)node * 4 + fg];
                    else if (fg < 68)  v = x1[(size_t)node * 64 + (fg - 4)];
                    else if (fg < 132) v = x2[(size_t)node * 64 + (fg - 68)];
                    else               v = x3[(size_t)node * 64 + (fg - 132)];
                    ft[r * 100 + f] = v;
                }
            }
            __syncthreads();
            int FSN = half ? 24 : 25;
            for (int fs = 0; fs < FSN; fs++) {
                float4 fv[4], wv[4];
#pragma unroll
                for (int rm = 0; rm < 4; rm++) fv[rm] = *(const float4*)&ft[(ty + 16 * rm) * 100 + fs * 4];
#pragma unroll
                for (int ca = 0; ca < 4; ca++) wv[ca] = *(const float4*)&wT[(tx + 16 * ca) * 100 + fs * 4];
#pragma unroll
                for (int rm = 0; rm < 4; rm++)
#pragma unroll
                    for (int ca = 0; ca < 4; ca++) {
                        acc[rm][ca] = fmaf(fv[rm].x, wv[ca].x, acc[rm][ca]);
                        acc[rm][ca] = fmaf(fv[rm].y, wv[ca].y, acc[rm][ca]);
                        acc[rm][ca] = fmaf(fv[rm].z, wv[ca].z, acc[rm][ca]);
                        acc[rm][ca] = fmaf(fv[rm].w, wv[ca].w, acc[rm][ca]);
                    }
            }
        }
#pragma unroll
        for (int rm = 0; rm < 4; rm++)
#pragma unroll
            for (int ca = 0; ca < 4; ca++) psum[ca] += lk(acc[rm][ca] + b1r[ca]);
    }
    __syncthreads();
    float* red = ft;  // 16 x 64
#pragma unroll
    for (int ca = 0; ca < 4; ca++) red[ty * 64 + tx + 16 * ca] = psum[ca];
    __syncthreads();
    if (threadIdx.x < 64) {
        float tot = 0.f;
#pragma unroll
        for (int t = 0; t < 16; t++) tot += red[t * 64 + threadIdx.x];
        Hsum[g * 512 + cch * 64 + threadIdx.x] = tot;
    }
}

// ------------------------------------------------------------- per-graph head
__global__ __launch_bounds__(256) void k_final(const float* __restrict__ Hsum,
                                               const unsigned int* __restrict__ hcnt,
                                               const float* __restrict__ l1w2,
                                               const float* __restrict__ l1b2,
                                               const float* __restrict__ mw1,
                                               const float* __restrict__ mb1,
                                               const float* __restrict__ mw2,
                                               const float* __restrict__ mb2,
                                               float* __restrict__ out) {
    __shared__ float Hb[512];
    __shared__ float z[260];
    __shared__ float y[256];
    int g = blockIdx.x, t = threadIdx.x;
    Hb[t] = Hsum[g * 512 + t] * (1.f / 2048.f);
    Hb[t + 256] = Hsum[g * 512 + 256 + t] * (1.f / 2048.f);
    __syncthreads();
    float acc = l1b2[t];
    for (int f = 0; f < 512; f++) acc = fmaf(Hb[f], l1w2[f * 256 + t], acc);
    z[t] = lk(acc);
    if (t < 4) z[256 + t] = lk((float)hcnt[g * 4 + t] * (1.f / (2048.f * 50.f)));
    __syncthreads();
    float acc2 = mb1[t];
    for (int f = 0; f < 260; f++) acc2 = fmaf(z[f], mw1[f * 256 + t], acc2);
    y[t] = lk(acc2);
    __syncthreads();
    if (t < 3) {
        float a = mb2[t];
        for (int c = 0; c < 256; c++) a = fmaf(y[c], mw2[c * 3 + t], a);
        out[g * 3 + t] = a;
    }
}

// ------------------------------------------------------------------ launcher
extern "C" void kernel_launch(void* const* d_in, const int* in_sizes, int n_in,
                              void* d_out, int out_size, void* d_ws, size_t ws_size,
                              hipStream_t stream) {
    (void)in_sizes; (void)n_in; (void)out_size; (void)ws_size;
    const float* x    = (const float*)d_in[0];
    const float* pos  = (const float*)d_in[1];
    const float* c1w1 = (const float*)d_in[3];
    const float* c1b1 = (const float*)d_in[4];
    const float* c1w2 = (const float*)d_in[5];
    const float* c1b2 = (const float*)d_in[6];
    const float* c2w1 = (const float*)d_in[7];
    const float* c2b1 = (const float*)d_in[8];
    const float* c2w2 = (const float*)d_in[9];
    const float* c2b2 = (const float*)d_in[10];
    const float* l1w1 = (const float*)d_in[11];
    const float* l1b1 = (const float*)d_in[12];
    const float* l1w2 = (const float*)d_in[13];
    const float* l1b2 = (const float*)d_in[14];
    const float* mw1  = (const float*)d_in[15];
    const float* mb1  = (const float*)d_in[16];
    const float* mw2  = (const float*)d_in[17];
    const float* mb2  = (const float*)d_in[18];
    float* out = (float*)d_out;

    char* w = (char*)d_ws;
    auto alloc = [&](size_t bytes) -> void* {
        void* r = (void*)w;
        w += (bytes + 255) & ~(size_t)255;
        return r;
    };
    float* xx   = (float*)alloc((size_t)BN * 4 * 4);
    float* pbuf = (float*)alloc((size_t)BN * 128 * 4);
    float* qbuf = (float*)alloc((size_t)BN * 128 * 4);
    float* x1   = (float*)alloc((size_t)BN * 64 * 4);
    float* x2   = (float*)alloc((size_t)BN * 64 * 4);
    float* x3   = (float*)alloc((size_t)BN * 64 * 4);
    float* sbuf = (float*)alloc((size_t)BN * 4);
    int* c1i    = (int*)alloc((size_t)BN * 5 * 4);
    int* c2i    = (int*)alloc((size_t)BN * 5 * 4);
    int* c3i    = (int*)alloc((size_t)BN * 5 * 4);
    unsigned int* hcnt = (unsigned int*)alloc(32 * 4 * 4);
    float* Hsum = (float*)alloc(32 * 512 * 4);

    hipMemsetAsync(hcnt, 0, 32 * 4 * 4, stream);
    k_build_xx<<<BN / 256, 256, 0, stream>>>(x, pos, xx);
    k_knn4<<<BN / 4, 256, 0, stream>>>(xx, c1i, hcnt);
    // conv1
    k_pq<4, 64><<<dim3(BN / 64, 2), 256, 0, stream>>>(xx, c1w1, c1b1, pbuf, qbuf);
    k_edge<64><<<BN / 16, 256, 0, stream>>>(pbuf, qbuf, c1i, c1w2, c1b2, x1);
    // conv2
    k_sq<<<BN / 256, 256, 0, stream>>>(x1, sbuf);
    k_knn64<<<dim3(32, 32), 256, 0, stream>>>(x1, sbuf, c2i);
    k_pq<64, 128><<<dim3(BN / 64, 4), 256, 0, stream>>>(x1, c2w1, c2b1, pbuf, qbuf);
    k_edge<128><<<BN / 16, 256, 0, stream>>>(pbuf, qbuf, c2i, c2w2, c2b2, x2);
    // conv3 (shared conv2 weights)
    k_sq<<<BN / 256, 256, 0, stream>>>(x2, sbuf);
    k_knn64<<<dim3(32, 32), 256, 0, stream>>>(x2, sbuf, c3i);
    k_pq<64, 128><<<dim3(BN / 64, 4), 256, 0, stream>>>(x2, c2w1, c2b1, pbuf, qbuf);
    k_edge<128><<<BN / 16, 256, 0, stream>>>(pbuf, qbuf, c3i, c2w2, c2b2, x3);
    // lin1 layer1 + pool, then head
    k_lin1<<<dim3(8, 32), 256, 0, stream>>>(xx, x1, x2, x3, l1w1, l1b1, Hsum);
    k_final<<<32, 256, 0, stream>>>(Hsum, hcnt, l1w2, l1b2, mw1, mb1, mw2, mb2, out);
}

// Round 2
// 3859.497 us; speedup vs baseline: 2.8186x; 2.8186x over previous
//
#include <hip/hip_runtime.h>

static constexpr int B = 32, N = 2048, BN = B * N;

#define DEV static __device__ __forceinline__

DEV float lk(float v) { return v >= 0.f ? v : 0.01f * v; }
DEV bool lexlt(float d1, int j1, float d2, int j2) {
    return d1 < d2 || (d1 == d2 && j1 < j2);
}
DEV bool lexgt(float d1, int j1, float d2, int j2) {
    return d1 > d2 || (d1 == d2 && j1 > j2);
}

// ---------------------------------------------------------------- build xx
__global__ __launch_bounds__(256) void k_build_xx(const float* __restrict__ x,
                                                  const float* __restrict__ pos,
                                                  float* __restrict__ xx) {
    int i = blockIdx.x * 256 + threadIdx.x;
    if (i < BN) {
        float4 v;
        v.x = x[i];
        v.y = pos[3 * i + 0];
        v.z = pos[3 * i + 1];
        v.w = pos[3 * i + 2];
        ((float4*)xx)[i] = v;
    }
}

// ------------------------------------------------- knn(F=4) + homophily + conv1 idx
__global__ __launch_bounds__(256) void k_knn4(const float* __restrict__ xx,
                                              int* __restrict__ c1idx,
                                              unsigned int* __restrict__ hcnt) {
    int gw = (blockIdx.x * 256 + threadIdx.x) >> 6;  // global row id
    int lane = threadIdx.x & 63;
    int g = gw >> 11, i = gw & 2047;
    const float4* base = ((const float4*)xx) + g * N;
    float4 xi = base[i];
    float si = xi.x * xi.x + xi.y * xi.y + xi.z * xi.z + xi.w * xi.w;
    float d[32];
#pragma unroll
    for (int t = 0; t < 32; t++) {
        float4 xj = base[lane + 64 * t];
        float sj = xj.x * xj.x + xj.y * xj.y + xj.z * xj.z + xj.w * xj.w;
        float dot = xi.x * xj.x + xi.y * xj.y + xi.z * xj.z + xi.w * xj.w;
        d[t] = (si + sj) - 2.f * dot;
    }
    float Lv[4];
    int Lj[4];
#pragma unroll
    for (int s = 0; s < 4; s++) { Lv[s] = __builtin_inff(); Lj[s] = 0x7fffffff; }
#pragma unroll 4
    for (int t = 0; t < 32; t++) {
        float v = d[t];
        int j = lane + 64 * t;
        if (lexlt(v, j, Lv[3], Lj[3])) {
            Lv[3] = v; Lj[3] = j;
#pragma unroll
            for (int s = 3; s >= 1; s--)
                if (lexlt(Lv[s], Lj[s], Lv[s - 1], Lj[s - 1])) {
                    float tv = Lv[s]; Lv[s] = Lv[s - 1]; Lv[s - 1] = tv;
                    int tj = Lj[s]; Lj[s] = Lj[s - 1]; Lj[s - 1] = tj;
                }
        }
    }
    int c0 = 0, c1 = 0, c2 = 0, c3 = 0, hc = 0;
    for (int r = 0; r < 51; r++) {
        float bv = Lv[0];
        int bj = Lj[0];
#pragma unroll
        for (int o = 1; o < 64; o <<= 1) {
            float ov = __shfl_xor(bv, o);
            int oj = __shfl_xor(bj, o);
            if (lexlt(ov, oj, bv, bj)) { bv = ov; bj = oj; }
        }
        if (r < 5 && lane == 0) c1idx[gw * 5 + r] = bj;
        if (bj != i && hc < 50) {
            hc++;
            if (lane == 0) {
                float4 xj = base[bj];
                c0 += (xj.x == xi.x); c1 += (xj.y == xi.y);
                c2 += (xj.z == xi.z); c3 += (xj.w == xi.w);
            }
        }
        if (Lv[0] == bv && Lj[0] == bj) {
            Lv[0] = Lv[1]; Lv[1] = Lv[2]; Lv[2] = Lv[3]; Lv[3] = __builtin_inff();
            Lj[0] = Lj[1]; Lj[1] = Lj[2]; Lj[2] = Lj[3]; Lj[3] = 0x7fffffff;
            if (Lv[0] == __builtin_inff() && Lj[0] == 0x7fffffff) {
#pragma unroll 4
                for (int t = 0; t < 32; t++) {
                    float v = d[t];
                    int j = lane + 64 * t;
                    if (lexgt(v, j, bv, bj) && lexlt(v, j, Lv[3], Lj[3])) {
                        Lv[3] = v; Lj[3] = j;
#pragma unroll
                        for (int s = 3; s >= 1; s--)
                            if (lexlt(Lv[s], Lj[s], Lv[s - 1], Lj[s - 1])) {
                                float tv = Lv[s]; Lv[s] = Lv[s - 1]; Lv[s - 1] = tv;
                                int tj = Lj[s]; Lj[s] = Lj[s - 1]; Lj[s - 1] = tj;
                            }
                    }
                }
            }
        }
    }
    if (lane == 0) {
        unsigned int* hp = hcnt + g * 4;
        atomicAdd(hp + 0, (unsigned)c0);
        atomicAdd(hp + 1, (unsigned)c1);
        atomicAdd(hp + 2, (unsigned)c2);
        atomicAdd(hp + 3, (unsigned)c3);
    }
}

// ---------------------------------------------------------------- squared norms
__global__ __launch_bounds__(256) void k_sq(const float* __restrict__ X,
                                            float* __restrict__ s) {
    int n = blockIdx.x * 256 + threadIdx.x;
    const float4* r = (const float4*)(X + (size_t)n * 64);
    float acc = 0.f;
#pragma unroll
    for (int t = 0; t < 16; t++) {
        float4 v = r[t];
        acc += v.x * v.x + v.y * v.y + v.z * v.z + v.w * v.w;
    }
    s[n] = acc;
}

// ----------------------------------------- node-level layer-1 split: p = x(Wa-Wb)+b1, q = x Wb
template <int F, int C>
__global__ __launch_bounds__(256, 4) void k_pq(const float* __restrict__ X,
                                               const float* __restrict__ w1,
                                               const float* __restrict__ b1,
                                               float* __restrict__ p,
                                               float* __restrict__ q) {
    constexpr int FS = F + 4;
    __shared__ __align__(16) float Xs[64 * FS];
    __shared__ __align__(16) float Ws[64 * FS];
    int nbase = blockIdx.x * 64;
    int cchunk = blockIdx.y;
    int tx = threadIdx.x & 15, ty = threadIdx.x >> 4;
    // vectorized X staging (rows are F floats, F%4==0)
    for (int idx = threadIdx.x; idx < 64 * (F / 4); idx += 256) {
        int r = idx / (F / 4), fq = idx % (F / 4);
        float4 v = ((const float4*)(X + (size_t)(nbase + r) * F))[fq];
        *(float4*)&Xs[r * FS + fq * 4] = v;
    }
    for (int idx = threadIdx.x; idx < 64 * F; idx += 256) {
        int f = idx >> 6, cl = idx & 63;
        int ccg = cchunk * 64 + cl;
        float v;
        if (ccg < C) v = w1[f * C + ccg] - w1[(F + f) * C + ccg];
        else         v = w1[(F + f) * C + (ccg - C)];
        Ws[cl * FS + f] = v;
    }
    __syncthreads();
    float acc[4][4];
#pragma unroll
    for (int a = 0; a < 4; a++)
#pragma unroll
        for (int b = 0; b < 4; b++) acc[a][b] = 0.f;
#pragma unroll 2
    for (int fs = 0; fs < F / 4; fs++) {
        float4 xv[4], wv[4];
#pragma unroll
        for (int a = 0; a < 4; a++) xv[a] = *(const float4*)&Xs[(ty + 16 * a) * FS + fs * 4];
#pragma unroll
        for (int b = 0; b < 4; b++) wv[b] = *(const float4*)&Ws[(tx + 16 * b) * FS + fs * 4];
#pragma unroll
        for (int a = 0; a < 4; a++)
#pragma unroll
            for (int b = 0; b < 4; b++) {
                acc[a][b] = fmaf(xv[a].x, wv[b].x, acc[a][b]);
                acc[a][b] = fmaf(xv[a].y, wv[b].y, acc[a][b]);
                acc[a][b] = fmaf(xv[a].z, wv[b].z, acc[a][b]);
                acc[a][b] = fmaf(xv[a].w, wv[b].w, acc[a][b]);
            }
    }
#pragma unroll
    for (int a = 0; a < 4; a++) {
        int n = nbase + ty + 16 * a;
#pragma unroll
        for (int b = 0; b < 4; b++) {
            int ccg = cchunk * 64 + tx + 16 * b;
            if (ccg < C) p[(size_t)n * C + ccg] = acc[a][b] + b1[ccg];
            else         q[(size_t)n * C + (ccg - C)] = acc[a][b];
        }
    }
}

// --------------------------------- per-edge layer 2: h2 = leaky(h1 @ w2 + b2), sum over k=5
template <int C1>
__global__ __launch_bounds__(256, 4) void k_edge(const float* __restrict__ p,
                                                 const float* __restrict__ q,
                                                 const int* __restrict__ cidx,
                                                 const float* __restrict__ w2,
                                                 const float* __restrict__ b2,
                                                 float* __restrict__ Xout) {
    __shared__ __align__(16) float h1[80 * 68];
    __shared__ __align__(16) float w2T[64 * 68];
    int nb = blockIdx.x * 16;
    int gb = (nb >> 11) << 11;  // graph base node
    int tx = threadIdx.x & 15, ty = threadIdx.x >> 4;
    float acc[5][4];
#pragma unroll
    for (int m = 0; m < 5; m++)
#pragma unroll
        for (int n = 0; n < 4; n++) acc[m][n] = 0.f;
#pragma unroll 1
    for (int half = 0; half < C1 / 64; half++) {
        __syncthreads();
        for (int idx = threadIdx.x; idx < 64 * 64; idx += 256) {
            int l = idx >> 6, c = idx & 63;
            w2T[c * 68 + l] = w2[(half * 64 + l) * 64 + c];
        }
        // vectorized h1 staging: each edge row is 64 floats = 16 float4
        for (int idx = threadIdx.x; idx < 80 * 16; idx += 256) {
            int e = idx >> 4, fq = idx & 15;
            int node = nb + e / 5, kk = e - 5 * (e / 5);
            int j = cidx[node * 5 + kk];
            float4 pv = ((const float4*)(p + (size_t)node * C1 + half * 64))[fq];
            float4 qv = ((const float4*)(q + (size_t)(gb + j) * C1 + half * 64))[fq];
            float4 hv;
            hv.x = lk(pv.x + qv.x); hv.y = lk(pv.y + qv.y);
            hv.z = lk(pv.z + qv.z); hv.w = lk(pv.w + qv.w);
            *(float4*)&h1[e * 68 + fq * 4] = hv;
        }
        __syncthreads();
#pragma unroll 1
        for (int ls = 0; ls < 16; ls++) {
            float4 hv[5], wf[4];
#pragma unroll
            for (int m = 0; m < 5; m++) hv[m] = *(const float4*)&h1[(ty + 16 * m) * 68 + ls * 4];
#pragma unroll
            for (int n = 0; n < 4; n++) wf[n] = *(const float4*)&w2T[(tx + 16 * n) * 68 + ls * 4];
#pragma unroll
            for (int m = 0; m < 5; m++)
#pragma unroll
                for (int n = 0; n < 4; n++) {
                    acc[m][n] = fmaf(hv[m].x, wf[n].x, acc[m][n]);
                    acc[m][n] = fmaf(hv[m].y, wf[n].y, acc[m][n]);
                    acc[m][n] = fmaf(hv[m].z, wf[n].z, acc[m][n]);
                    acc[m][n] = fmaf(hv[m].w, wf[n].w, acc[m][n]);
                }
        }
    }
    float b2r[4];
#pragma unroll
    for (int n = 0; n < 4; n++) b2r[n] = b2[tx + 16 * n];
    __syncthreads();  // all h1 reads done; reuse h1 region for h2
    float* h2 = h1;
#pragma unroll
    for (int m = 0; m < 5; m++)
#pragma unroll
        for (int n = 0; n < 4; n++)
            h2[(ty + 16 * m) * 68 + (tx + 16 * n)] = lk(acc[m][n] + b2r[n]);
    __syncthreads();
#pragma unroll
    for (int rr = 0; rr < 4; rr++) {
        int idx = threadIdx.x + 256 * rr;
        int node = idx >> 6, c = idx & 63;
        float sum = 0.f;
#pragma unroll
        for (int kk = 0; kk < 5; kk++) sum += h2[(node * 5 + kk) * 68 + c];
        Xout[(size_t)(nb + node) * 64 + c] = sum;
    }
}

// --------------------------------------------- knn over F=64 features, top-5 (self incl.)
__global__ __launch_bounds__(256, 4) void k_knn64(const float* __restrict__ X,
                                                  const float* __restrict__ s,
                                                  int* __restrict__ cidx) {
    __shared__ __align__(16) float Xi[64 * 68];
    __shared__ __align__(16) float Xj[64 * 68];  // reused as cand buffer in merge
    __shared__ float sI[64], sJ[64];
    int it = blockIdx.x, g = blockIdx.y;
    int gbase = g * 2048, ibase = it * 64;
    int tx = threadIdx.x & 15, ty = threadIdx.x >> 4;
    for (int idx = threadIdx.x; idx < 64 * 16; idx += 256) {
        int r = idx >> 4, fq = idx & 15;
        float4 v = ((const float4*)(X + (size_t)(gbase + ibase + r) * 64))[fq];
        *(float4*)&Xi[r * 68 + fq * 4] = v;
    }
    if (threadIdx.x < 64) sI[threadIdx.x] = s[gbase + ibase + threadIdx.x];
    __syncthreads();
    float si_r[4];
#pragma unroll
    for (int a = 0; a < 4; a++) si_r[a] = sI[ty + 16 * a];
    float t5v[4][5];
    int t5j[4][5];
#pragma unroll
    for (int a = 0; a < 4; a++)
#pragma unroll
        for (int ss = 0; ss < 5; ss++) { t5v[a][ss] = __builtin_inff(); t5j[a][ss] = 0x7fffffff; }
    for (int jt = 0; jt < 32; jt++) {
        __syncthreads();
        for (int idx = threadIdx.x; idx < 64 * 16; idx += 256) {
            int r = idx >> 4, fq = idx & 15;
            float4 v = ((const float4*)(X + (size_t)(gbase + jt * 64 + r) * 64))[fq];
            *(float4*)&Xj[r * 68 + fq * 4] = v;
        }
        if (threadIdx.x < 64) sJ[threadIdx.x] = s[gbase + jt * 64 + threadIdx.x];
        __syncthreads();
        float sj_r[4];
#pragma unroll
        for (int b = 0; b < 4; b++) sj_r[b] = sJ[tx + 16 * b];
        float acc[4][4];
#pragma unroll
        for (int a = 0; a < 4; a++)
#pragma unroll
            for (int b = 0; b < 4; b++) acc[a][b] = 0.f;
#pragma unroll 1
        for (int fs = 0; fs < 16; fs++) {
            float4 xa[4], xb[4];
#pragma unroll
            for (int a = 0; a < 4; a++) xa[a] = *(const float4*)&Xi[(ty + 16 * a) * 68 + fs * 4];
#pragma unroll
            for (int b = 0; b < 4; b++) xb[b] = *(const float4*)&Xj[(tx + 16 * b) * 68 + fs * 4];
#pragma unroll
            for (int a = 0; a < 4; a++)
#pragma unroll
                for (int b = 0; b < 4; b++) {
                    acc[a][b] = fmaf(xa[a].x, xb[b].x, acc[a][b]);
                    acc[a][b] = fmaf(xa[a].y, xb[b].y, acc[a][b]);
                    acc[a][b] = fmaf(xa[a].z, xb[b].z, acc[a][b]);
                    acc[a][b] = fmaf(xa[a].w, xb[b].w, acc[a][b]);
                }
        }
#pragma unroll
        for (int a = 0; a < 4; a++)
#pragma unroll
            for (int b = 0; b < 4; b++) {
                float dv = (si_r[a] + sj_r[b]) - 2.f * acc[a][b];
                int jv = jt * 64 + tx + 16 * b;
                if (lexlt(dv, jv, t5v[a][4], t5j[a][4])) {
                    t5v[a][4] = dv; t5j[a][4] = jv;
#pragma unroll
                    for (int ss = 4; ss >= 1; ss--)
                        if (lexlt(t5v[a][ss], t5j[a][ss], t5v[a][ss - 1], t5j[a][ss - 1])) {
                            float tv = t5v[a][ss]; t5v[a][ss] = t5v[a][ss - 1]; t5v[a][ss - 1] = tv;
                            int tj = t5j[a][ss]; t5j[a][ss] = t5j[a][ss - 1]; t5j[a][ss - 1] = tj;
                        }
                }
            }
    }
    // merge in 4 phases (one per a), reusing Xj as candidate buffer
    float* candd = Xj;                     // 16 rows x 80 cand
    int* candj = (int*)(Xj + 16 * 80);
#pragma unroll 1
    for (int a = 0; a < 4; a++) {
        __syncthreads();
#pragma unroll
        for (int ss = 0; ss < 5; ss++) {
            candd[ty * 80 + tx * 5 + ss] = t5v[a][ss];
            candj[ty * 80 + tx * 5 + ss] = t5j[a][ss];
        }
        __syncthreads();
        if (threadIdx.x < 16) {
            int t = threadIdx.x;
            float fv[5];
            int fj[5];
#pragma unroll
            for (int ss = 0; ss < 5; ss++) { fv[ss] = __builtin_inff(); fj[ss] = 0x7fffffff; }
#pragma unroll 1
            for (int c = 0; c < 80; c++) {
                float dv = candd[t * 80 + c];
                int jv = candj[t * 80 + c];
                if (lexlt(dv, jv, fv[4], fj[4])) {
                    fv[4] = dv; fj[4] = jv;
#pragma unroll
                    for (int ss = 4; ss >= 1; ss--)
                        if (lexlt(fv[ss], fj[ss], fv[ss - 1], fj[ss - 1])) {
                            float tv = fv[ss]; fv[ss] = fv[ss - 1]; fv[ss - 1] = tv;
                            int tj = fj[ss]; fj[ss] = fj[ss - 1]; fj[ss - 1] = tj;
                        }
                }
            }
#pragma unroll
            for (int ss = 0; ss < 5; ss++)
                cidx[(size_t)(gbase + ibase + 16 * a + t) * 5 + ss] = fj[ss];
        }
    }
}

// ------------------------- lin1 layer1 + leaky + mean-pool accumulate (no atomics)
// block = (cchunk 0..7, graph, quarter 0..3); each quarter covers 8 node-tiles.
__global__ __launch_bounds__(256, 3) void k_lin1(const float* __restrict__ xx,
                                                 const float* __restrict__ x1,
                                                 const float* __restrict__ x2,
                                                 const float* __restrict__ x3,
                                                 const float* __restrict__ w1,
                                                 const float* __restrict__ b1,
                                                 float* __restrict__ Hpart) {
    __shared__ __align__(16) float ft[64 * 100];
    __shared__ __align__(16) float wT[64 * 100];
    int cch = blockIdx.x, g = blockIdx.y, z = blockIdx.z;
    int gbase = g * 2048;
    int tx = threadIdx.x & 15, ty = threadIdx.x >> 4;
    float b1r[4];
#pragma unroll
    for (int ca = 0; ca < 4; ca++) b1r[ca] = b1[cch * 64 + tx + 16 * ca];
    float psum[4] = {0.f, 0.f, 0.f, 0.f};
#pragma unroll 1
    for (int nt = z * 8; nt < z * 8 + 8; nt++) {
        int n0 = nt * 64;
        float acc[4][4];
#pragma unroll
        for (int rm = 0; rm < 4; rm++)
#pragma unroll
            for (int ca = 0; ca < 4; ca++) acc[rm][ca] = 0.f;
#pragma unroll 1
        for (int half = 0; half < 2; half++) {
            int fb = half * 100;
            int FH = half ? 96 : 100;
            __syncthreads();
            for (int idx = threadIdx.x; idx < 64 * 100; idx += 256) {
                int f = idx >> 6, cl = idx & 63;
                if (f < FH) wT[cl * 100 + f] = w1[(fb + f) * 512 + cch * 64 + cl];
            }
            for (int idx = threadIdx.x; idx < 64 * 100; idx += 256) {
                int r = idx / 100, f = idx - r * 100;
                if (f < FH) {
                    int fg = fb + f;
                    int node = gbase + n0 + r;
                    float v;
                    if (fg < 4)        v = xx[(size_t)node * 4 + fg];
                    else if (fg < 68)  v = x1[(size_t)node * 64 + (fg - 4)];
                    else if (fg < 132) v = x2[(size_t)node * 64 + (fg - 68)];
                    else               v = x3[(size_t)node * 64 + (fg - 132)];
                    ft[r * 100 + f] = v;
                }
            }
            __syncthreads();
            int FSN = half ? 24 : 25;
#pragma unroll 2
            for (int fs = 0; fs < FSN; fs++) {
                float4 fv[4], wv[4];
#pragma unroll
                for (int rm = 0; rm < 4; rm++) fv[rm] = *(const float4*)&ft[(ty + 16 * rm) * 100 + fs * 4];
#pragma unroll
                for (int ca = 0; ca < 4; ca++) wv[ca] = *(const float4*)&wT[(tx + 16 * ca) * 100 + fs * 4];
#pragma unroll
                for (int rm = 0; rm < 4; rm++)
#pragma unroll
                    for (int ca = 0; ca < 4; ca++) {
                        acc[rm][ca] = fmaf(fv[rm].x, wv[ca].x, acc[rm][ca]);
                        acc[rm][ca] = fmaf(fv[rm].y, wv[ca].y, acc[rm][ca]);
                        acc[rm][ca] = fmaf(fv[rm].z, wv[ca].z, acc[rm][ca]);
                        acc[rm][ca] = fmaf(fv[rm].w, wv[ca].w, acc[rm][ca]);
                    }
            }
        }
#pragma unroll
        for (int rm = 0; rm < 4; rm++)
#pragma unroll
            for (int ca = 0; ca < 4; ca++) psum[ca] += lk(acc[rm][ca] + b1r[ca]);
    }
    __syncthreads();
    float* red = ft;  // 16 x 64
#pragma unroll
    for (int ca = 0; ca < 4; ca++) red[ty * 64 + tx + 16 * ca] = psum[ca];
    __syncthreads();
    if (threadIdx.x < 64) {
        float tot = 0.f;
#pragma unroll
        for (int t = 0; t < 16; t++) tot += red[t * 64 + threadIdx.x];
        Hpart[((size_t)z * 32 + g) * 512 + cch * 64 + threadIdx.x] = tot;
    }
}

// ------------------------------------------------------------- per-graph head
__global__ __launch_bounds__(256) void k_final(const float* __restrict__ Hpart,
                                               const unsigned int* __restrict__ hcnt,
                                               const float* __restrict__ l1w2,
                                               const float* __restrict__ l1b2,
                                               const float* __restrict__ mw1,
                                               const float* __restrict__ mb1,
                                               const float* __restrict__ mw2,
                                               const float* __restrict__ mb2,
                                               float* __restrict__ out) {
    __shared__ float Hb[512];
    __shared__ float z[260];
    __shared__ float y[256];
    int g = blockIdx.x, t = threadIdx.x;
#pragma unroll
    for (int half = 0; half < 2; half++) {
        int c = t + 256 * half;
        float v = 0.f;
#pragma unroll
        for (int zz = 0; zz < 4; zz++) v += Hpart[((size_t)zz * 32 + g) * 512 + c];
        Hb[c] = v * (1.f / 2048.f);
    }
    __syncthreads();
    float acc = l1b2[t];
    for (int f = 0; f < 512; f++) acc = fmaf(Hb[f], l1w2[f * 256 + t], acc);
    z[t] = lk(acc);
    if (t < 4) z[256 + t] = lk((float)hcnt[g * 4 + t] * (1.f / (2048.f * 50.f)));
    __syncthreads();
    float acc2 = mb1[t];
    for (int f = 0; f < 260; f++) acc2 = fmaf(z[f], mw1[f * 256 + t], acc2);
    y[t] = lk(acc2);
    __syncthreads();
    if (t < 3) {
        float a = mb2[t];
        for (int c = 0; c < 256; c++) a = fmaf(y[c], mw2[c * 3 + t], a);
        out[g * 3 + t] = a;
    }
}

// ------------------------------------------------------------------ launcher
extern "C" void kernel_launch(void* const* d_in, const int* in_sizes, int n_in,
                              void* d_out, int out_size, void* d_ws, size_t ws_size,
                              hipStream_t stream) {
    (void)in_sizes; (void)n_in; (void)out_size; (void)ws_size;
    const float* x    = (const float*)d_in[0];
    const float* pos  = (const float*)d_in[1];
    const float* c1w1 = (const float*)d_in[3];
    const float* c1b1 = (const float*)d_in[4];
    const float* c1w2 = (const float*)d_in[5];
    const float* c1b2 = (const float*)d_in[6];
    const float* c2w1 = (const float*)d_in[7];
    const float* c2b1 = (const float*)d_in[8];
    const float* c2w2 = (const float*)d_in[9];
    const float* c2b2 = (const float*)d_in[10];
    const float* l1w1 = (const float*)d_in[11];
    const float* l1b1 = (const float*)d_in[12];
    const float* l1w2 = (const float*)d_in[13];
    const float* l1b2 = (const float*)d_in[14];
    const float* mw1  = (const float*)d_in[15];
    const float* mb1  = (const float*)d_in[16];
    const float* mw2  = (const float*)d_in[17];
    const float* mb2  = (const float*)d_in[18];
    float* out = (float*)d_out;

    char* w = (char*)d_ws;
    auto alloc = [&](size_t bytes) -> void* {
        void* r = (void*)w;
        w += (bytes + 255) & ~(size_t)255;
        return r;
    };
    float* xx   = (float*)alloc((size_t)BN * 4 * 4);
    float* pbuf = (float*)alloc((size_t)BN * 128 * 4);
    float* qbuf = (float*)alloc((size_t)BN * 128 * 4);
    float* x1   = (float*)alloc((size_t)BN * 64 * 4);
    float* x2   = (float*)alloc((size_t)BN * 64 * 4);
    float* x3   = (float*)alloc((size_t)BN * 64 * 4);
    float* sbuf = (float*)alloc((size_t)BN * 4);
    int* c1i    = (int*)alloc((size_t)BN * 5 * 4);
    int* c2i    = (int*)alloc((size_t)BN * 5 * 4);
    int* c3i    = (int*)alloc((size_t)BN * 5 * 4);
    unsigned int* hcnt = (unsigned int*)alloc(32 * 4 * 4);
    float* Hpart = (float*)alloc((size_t)4 * 32 * 512 * 4);

    hipMemsetAsync(hcnt, 0, 32 * 4 * 4, stream);
    k_build_xx<<<BN / 256, 256, 0, stream>>>(x, pos, xx);
    k_knn4<<<BN / 4, 256, 0, stream>>>(xx, c1i, hcnt);
    // conv1
    k_pq<4, 64><<<dim3(BN / 64, 2), 256, 0, stream>>>(xx, c1w1, c1b1, pbuf, qbuf);
    k_edge<64><<<BN / 16, 256, 0, stream>>>(pbuf, qbuf, c1i, c1w2, c1b2, x1);
    // conv2
    k_sq<<<BN / 256, 256, 0, stream>>>(x1, sbuf);
    k_knn64<<<dim3(32, 32), 256, 0, stream>>>(x1, sbuf, c2i);
    k_pq<64, 128><<<dim3(BN / 64, 4), 256, 0, stream>>>(x1, c2w1, c2b1, pbuf, qbuf);
    k_edge<128><<<BN / 16, 256, 0, stream>>>(pbuf, qbuf, c2i, c2w2, c2b2, x2);
    // conv3 (shared conv2 weights)
    k_sq<<<BN / 256, 256, 0, stream>>>(x2, sbuf);
    k_knn64<<<dim3(32, 32), 256, 0, stream>>>(x2, sbuf, c3i);
    k_pq<64, 128><<<dim3(BN / 64, 4), 256, 0, stream>>>(x2, c2w1, c2b1, pbuf, qbuf);
    k_edge<128><<<BN / 16, 256, 0, stream>>>(pbuf, qbuf, c3i, c2w2, c2b2, x3);
    // lin1 layer1 + pool (4-way split), then head
    k_lin1<<<dim3(8, 32, 4), 256, 0, stream>>>(xx, x1, x2, x3, l1w1, l1b1, Hpart);
    k_final<<<32, 256, 0, stream>>>(Hpart, hcnt, l1w2, l1b2, mw1, mb1, mw2, mb2, out);
}